// Round 16
// baseline (85.056 us; speedup 1.0000x reference)
//
#include <hip/hip_runtime.h>
#include <math.h>

typedef float v2f __attribute__((ext_vector_type(2)));

// Problem constants (fixed by setup_inputs)
constexpr int B_  = 8;
constexpr int C_  = 64;
constexpr int H_  = 112;
constexpr int W_  = 112;
constexpr int KH  = 5;
constexpr int KW  = 5;
constexpr int PAD = 2;

constexpr int TRT = 16;             // output rows per tile
constexpr int NT  = H_ / TRT;       // 7 tiles per plane
constexpr int LRT = TRT + KH - 1;   // 20 staged rows
constexpr int LCP = 118;            // v2f row stride (even -> rows 16B-aligned)
constexpr int TPB = 256;
constexpr int NINT = LRT * 28;      // 560 interior float4 staging items

// Execution barrier WITHOUT vmcnt drain (raw s_barrier + lgkm-only drain).
__device__ __forceinline__ void block_sync_lds() {
    asm volatile("s_waitcnt lgkmcnt(0)" ::: "memory");
    __builtin_amdgcn_sched_barrier(0);
    __builtin_amdgcn_s_barrier();
}

// ---------------------------------------------------------------------------
// Single-barrier software-pipelined soft-morphology (func_type==1):
//   iter t: compute(t) [ds_read+FMA+7 scalar stores]
//           || transform(t+1) [exp -> other LDS buffer]
//           || issue loads(t+2) [global -> regs]
//           one lgkm-drain barrier.
// Math (factored softmax): E=e^{a*s*x}, F=(s*x)E; u=e^{a*w}, v=w*u;
//   out = s*((corr(F,u)+corr(E,v))*rcp(corr(E,u))) + s*bias
// Packed: (Z,Nm) += (u,u)*(E,F) via v_pk_fma_f32; nm2 += v*E scalar.
// Zero-padded taps => E=1, F=0.
// ---------------------------------------------------------------------------
__global__ __launch_bounds__(TPB, 4)
void morpho_pipe(const float* __restrict__ x,
                 const float* __restrict__ weight,
                 const float* __restrict__ bias,
                 const float* __restrict__ sign,
                 const int*   __restrict__ alpha_p,
                 float* __restrict__ out)
{
    __shared__ __align__(16) char sraw[2 * LRT * LCP * sizeof(v2f)]; // 37760 B
    v2f (*sEF)[LRT][LCP] = reinterpret_cast<v2f (*)[LRT][LCP]>(sraw);

    const int plane = blockIdx.x;         // 0..511 (b*C + c)
    const int c     = plane & (C_ - 1);
    const int tid   = threadIdx.x;

    const float sg   = sign[0];
    const float seff = (fabsf(sg) >= 1e-7f) ? sg : 1.0f;
    const float a    = (float)alpha_p[0];
    const float aK   = a * seff;          // E = exp(aK * raw_x)

    const float* xp = x + (size_t)plane * (H_ * W_);
    float*       op = out + (size_t)plane * (H_ * W_);

    // per-item staging indices (fixed across iterations)
    int r_[3], q_[3];
    bool ok_[3];
#pragma unroll
    for (int k = 0; k < 3; ++k) {
        int i  = tid + TPB * k;               // 0..767
        int ic = (i < NINT) ? i : (NINT - 1);
        r_[k] = ic / 28;
        q_[k] = ic - 28 * r_[k];
        ok_[k] = (i < NINT);
    }

    float4 xc[3];
    // ---- issue tile-0 loads; weight transforms overlap their latency ----
#pragma unroll
    for (int k = 0; k < 3; ++k) {
        int grc = min(max(-PAD + r_[k], 0), H_ - 1);
        xc[k] = *reinterpret_cast<const float4*>(xp + grc * W_ + 4 * q_[k]);
    }

    const float* wp = weight + c * (KH * KW);
    float su[KH * KW], sv[KH * KW];
#pragma unroll
    for (int k = 0; k < KH * KW; ++k) {
        float wv = wp[k];
        float u  = __expf(a * wv);
        su[k] = u;
        sv[k] = wv * u;
    }
    const float sb = seff * bias[c];

    const int ty = tid >> 4;      // 0..15 : output row within tile
    const int tx = tid & 15;      // 0..15 : col group
    const int c0 = tx * 7;

    // transform tile 0 -> buf0, then issue tile-1 loads (in flight over barrier)
    {
        v2f (*buf)[LCP] = sEF[0];
#pragma unroll
        for (int k = 0; k < 3; ++k) {
            if (ok_[k]) {
                int gr = -PAD + r_[k];
                bool ok = (gr >= 0) && (gr < H_);
                float4 v = xc[k];
                float e0 = ok ? __expf(aK * v.x) : 1.0f;
                float e1 = ok ? __expf(aK * v.y) : 1.0f;
                float e2 = ok ? __expf(aK * v.z) : 1.0f;
                float e3 = ok ? __expf(aK * v.w) : 1.0f;
                float f0 = ok ? (seff * v.x) * e0 : 0.0f;
                float f1 = ok ? (seff * v.y) * e1 : 0.0f;
                float f2 = ok ? (seff * v.z) * e2 : 0.0f;
                float f3 = ok ? (seff * v.w) * e3 : 0.0f;
                float4* dst = reinterpret_cast<float4*>(&buf[r_[k]][2 + 4 * q_[k]]);
                dst[0] = make_float4(e0, f0, e1, f1);
                dst[1] = make_float4(e2, f2, e3, f3);
            }
        }
        if (tid < 2 * LRT) {
            int r  = tid >> 1;
            int fi = (tid & 1) ? 114 : 0;
            *reinterpret_cast<float4*>(&buf[r][fi]) = make_float4(1.0f, 0.0f, 1.0f, 0.0f);
        }
#pragma unroll
        for (int k = 0; k < 3; ++k) {      // tile-1 loads (WAR on xc is in-order safe)
            int grc = min(max(TRT - PAD + r_[k], 0), H_ - 1);
            xc[k] = *reinterpret_cast<const float4*>(xp + grc * W_ + 4 * q_[k]);
        }
    }
    block_sync_lds();

    for (int t = 0; t < NT; ++t) {
        v2f (*buf)[LCP] = sEF[t & 1];

        // ---- compute tile t: packed FMA + inline scalar stores ----
        v2f   acc[7];
        float nm2[7];
#pragma unroll
        for (int o = 0; o < 7; ++o) { acc[o] = (v2f){0.0f, 0.0f}; nm2[o] = 0.0f; }

#pragma unroll
        for (int rr = 0; rr < KH; ++rr) {
            v2f ew[11];
#pragma unroll
            for (int jj = 0; jj < 11; ++jj) ew[jj] = buf[ty + rr][c0 + jj];
#pragma unroll
            for (int j = 0; j < KW; ++j) {
                const float u  = su[rr * 5 + j];
                const v2f   u2 = (v2f){u, u};
                const float v  = sv[rr * 5 + j];
#pragma unroll
                for (int o = 0; o < 7; ++o) {
                    acc[o] = __builtin_elementwise_fma(u2, ew[o + j], acc[o]); // Z+=uE, Nm+=uF
                    nm2[o] = fmaf(v, ew[o + j].x, nm2[o]);                     // nm2+=vE
                }
            }
        }
        {
            float* orow = op + (size_t)(t * TRT + ty) * W_ + c0;
#pragma unroll
            for (int o = 0; o < 7; ++o) {
                float Z  = acc[o].x;
                float Nm = acc[o].y + nm2[o];
                orow[o] = fmaf(seff * Nm, __builtin_amdgcn_rcpf(Z), sb);
            }
        }

        // ---- transform tile t+1 (xc) into the other buffer ----
        if (t + 1 < NT) {
            v2f (*nbuf)[LCP] = sEF[(t + 1) & 1];
            const int nrow0 = (t + 1) * TRT - PAD;
#pragma unroll
            for (int k = 0; k < 3; ++k) {
                if (ok_[k]) {
                    int gr = nrow0 + r_[k];
                    bool ok = (gr >= 0) && (gr < H_);
                    float4 v = xc[k];
                    float e0 = ok ? __expf(aK * v.x) : 1.0f;
                    float e1 = ok ? __expf(aK * v.y) : 1.0f;
                    float e2 = ok ? __expf(aK * v.z) : 1.0f;
                    float e3 = ok ? __expf(aK * v.w) : 1.0f;
                    float f0 = ok ? (seff * v.x) * e0 : 0.0f;
                    float f1 = ok ? (seff * v.y) * e1 : 0.0f;
                    float f2 = ok ? (seff * v.z) * e2 : 0.0f;
                    float f3 = ok ? (seff * v.w) * e3 : 0.0f;
                    float4* dst = reinterpret_cast<float4*>(&nbuf[r_[k]][2 + 4 * q_[k]]);
                    dst[0] = make_float4(e0, f0, e1, f1);
                    dst[1] = make_float4(e2, f2, e3, f3);
                }
            }
            if (tid < 2 * LRT) {
                int r  = tid >> 1;
                int fi = (tid & 1) ? 114 : 0;
                *reinterpret_cast<float4*>(&nbuf[r][fi]) = make_float4(1.0f, 0.0f, 1.0f, 0.0f);
            }
        }

        // ---- issue tile t+2 loads (land during next iter's compute) ----
        if (t + 2 < NT) {
            const int lrow0 = (t + 2) * TRT - PAD;
#pragma unroll
            for (int k = 0; k < 3; ++k) {
                int grc = min(max(lrow0 + r_[k], 0), H_ - 1);
                xc[k] = *reinterpret_cast<const float4*>(xp + grc * W_ + 4 * q_[k]);
            }
        }

        block_sync_lds();   // single lgkm-drain barrier per iteration
    }
}

extern "C" void kernel_launch(void* const* d_in, const int* in_sizes, int n_in,
                              void* d_out, int out_size, void* d_ws, size_t ws_size,
                              hipStream_t stream) {
    // setup_inputs order: x, weight, bias, sign, padding, stride, func_type, alpha
    const float* x      = (const float*)d_in[0];
    const float* weight = (const float*)d_in[1];
    const float* bias   = (const float*)d_in[2];
    const float* sign   = (const float*)d_in[3];
    const int*   alpha  = (const int*)d_in[7];
    float* out = (float*)d_out;

    dim3 grid(B_ * C_);   // one block per plane
    morpho_pipe<<<grid, TPB, 0, stream>>>(x, weight, bias, sign, alpha, out);
}

// Round 17
// 25.082 us; speedup vs baseline: 3.3911x; 3.3911x over previous
//
#include <hip/hip_runtime.h>
#include <math.h>

typedef float v2f __attribute__((ext_vector_type(2)));

// Problem constants (fixed by setup_inputs)
constexpr int B_  = 8;
constexpr int C_  = 64;
constexpr int H_  = 112;
constexpr int W_  = 112;
constexpr int KH  = 5;
constexpr int KW  = 5;
constexpr int PAD = 2;

constexpr int TRT = 16;             // output rows per tile
constexpr int NT  = H_ / TRT;       // 7 tiles per plane
constexpr int LRT = TRT + KH - 1;   // 20 staged rows
constexpr int LCP = 118;            // v2f row stride (even -> rows 16B-aligned)
constexpr int TPB = 256;
constexpr int NINT = LRT * 28;      // 560 interior float4 staging items

// Execution barrier WITHOUT vmcnt drain (raw s_barrier + lgkm-only drain).
__device__ __forceinline__ void block_sync_lds() {
    asm volatile("s_waitcnt lgkmcnt(0)" ::: "memory");
    __builtin_amdgcn_sched_barrier(0);
    __builtin_amdgcn_s_barrier();
}

// ---------------------------------------------------------------------------
// Single-barrier software-pipelined soft-morphology (func_type==1):
//   iter t: compute(t) [ds_read+FMA+7 scalar stores]
//           || transform(t+1) [exp -> other LDS buffer]
//           || issue loads(t+2) [global -> regs]
//           one lgkm-drain barrier.
// Math (factored softmax): E=e^{a*s*x}, F=(s*x)E; u=e^{a*w}, v=w*u;
//   out = s*((corr(F,u)+corr(E,v))*rcp(corr(E,u))) + s*bias
// Packed: (Z,Nm) += (u,u)*(E,F) via v_pk_fma_f32; nm2 += v*E scalar.
// Zero-padded taps => E=1, F=0.
// NOTE: no second __launch_bounds__ arg — (256,4) capped VGPR at 64 and
// caused 8x FETCH amplification from scratch spills (round 16).
// ---------------------------------------------------------------------------
__global__ __launch_bounds__(TPB)
void morpho_pipe(const float* __restrict__ x,
                 const float* __restrict__ weight,
                 const float* __restrict__ bias,
                 const float* __restrict__ sign,
                 const int*   __restrict__ alpha_p,
                 float* __restrict__ out)
{
    __shared__ __align__(16) char sraw[2 * LRT * LCP * sizeof(v2f)]; // 37760 B
    v2f (*sEF)[LRT][LCP] = reinterpret_cast<v2f (*)[LRT][LCP]>(sraw);

    const int plane = blockIdx.x;         // 0..511 (b*C + c)
    const int c     = plane & (C_ - 1);
    const int tid   = threadIdx.x;

    const float sg   = sign[0];
    const float seff = (fabsf(sg) >= 1e-7f) ? sg : 1.0f;
    const float a    = (float)alpha_p[0];
    const float aK   = a * seff;          // E = exp(aK * raw_x)

    const float* xp = x + (size_t)plane * (H_ * W_);
    float*       op = out + (size_t)plane * (H_ * W_);

    // per-item staging indices (fixed across iterations)
    int r_[3], q_[3];
    bool ok_[3];
#pragma unroll
    for (int k = 0; k < 3; ++k) {
        int i  = tid + TPB * k;               // 0..767
        int ic = (i < NINT) ? i : (NINT - 1);
        r_[k] = ic / 28;
        q_[k] = ic - 28 * r_[k];
        ok_[k] = (i < NINT);
    }

    float4 xc[3];
    // ---- issue tile-0 loads; weight transforms overlap their latency ----
#pragma unroll
    for (int k = 0; k < 3; ++k) {
        int grc = min(max(-PAD + r_[k], 0), H_ - 1);
        xc[k] = *reinterpret_cast<const float4*>(xp + grc * W_ + 4 * q_[k]);
    }

    const float* wp = weight + c * (KH * KW);
    float su[KH * KW], sv[KH * KW];
#pragma unroll
    for (int k = 0; k < KH * KW; ++k) {
        float wv = wp[k];
        float u  = __expf(a * wv);
        su[k] = u;
        sv[k] = wv * u;
    }
    const float sb = seff * bias[c];

    const int ty = tid >> 4;      // 0..15 : output row within tile
    const int tx = tid & 15;      // 0..15 : col group
    const int c0 = tx * 7;

    // transform tile 0 -> buf0, then issue tile-1 loads (in flight over barrier)
    {
        v2f (*buf)[LCP] = sEF[0];
#pragma unroll
        for (int k = 0; k < 3; ++k) {
            if (ok_[k]) {
                int gr = -PAD + r_[k];
                bool ok = (gr >= 0) && (gr < H_);
                float4 v = xc[k];
                float e0 = ok ? __expf(aK * v.x) : 1.0f;
                float e1 = ok ? __expf(aK * v.y) : 1.0f;
                float e2 = ok ? __expf(aK * v.z) : 1.0f;
                float e3 = ok ? __expf(aK * v.w) : 1.0f;
                float f0 = ok ? (seff * v.x) * e0 : 0.0f;
                float f1 = ok ? (seff * v.y) * e1 : 0.0f;
                float f2 = ok ? (seff * v.z) * e2 : 0.0f;
                float f3 = ok ? (seff * v.w) * e3 : 0.0f;
                float4* dst = reinterpret_cast<float4*>(&buf[r_[k]][2 + 4 * q_[k]]);
                dst[0] = make_float4(e0, f0, e1, f1);
                dst[1] = make_float4(e2, f2, e3, f3);
            }
        }
        if (tid < 2 * LRT) {
            int r  = tid >> 1;
            int fi = (tid & 1) ? 114 : 0;
            *reinterpret_cast<float4*>(&buf[r][fi]) = make_float4(1.0f, 0.0f, 1.0f, 0.0f);
        }
#pragma unroll
        for (int k = 0; k < 3; ++k) {      // tile-1 loads (WAR on xc is in-order safe)
            int grc = min(max(TRT - PAD + r_[k], 0), H_ - 1);
            xc[k] = *reinterpret_cast<const float4*>(xp + grc * W_ + 4 * q_[k]);
        }
    }
    block_sync_lds();

    for (int t = 0; t < NT; ++t) {
        v2f (*buf)[LCP] = sEF[t & 1];

        // ---- compute tile t: packed FMA + inline scalar stores ----
        v2f   acc[7];
        float nm2[7];
#pragma unroll
        for (int o = 0; o < 7; ++o) { acc[o] = (v2f){0.0f, 0.0f}; nm2[o] = 0.0f; }

#pragma unroll
        for (int rr = 0; rr < KH; ++rr) {
            v2f ew[11];
#pragma unroll
            for (int jj = 0; jj < 11; ++jj) ew[jj] = buf[ty + rr][c0 + jj];
#pragma unroll
            for (int j = 0; j < KW; ++j) {
                const float u  = su[rr * 5 + j];
                const v2f   u2 = (v2f){u, u};
                const float v  = sv[rr * 5 + j];
#pragma unroll
                for (int o = 0; o < 7; ++o) {
                    acc[o] = __builtin_elementwise_fma(u2, ew[o + j], acc[o]); // Z+=uE, Nm+=uF
                    nm2[o] = fmaf(v, ew[o + j].x, nm2[o]);                     // nm2+=vE
                }
            }
        }
        {
            float* orow = op + (size_t)(t * TRT + ty) * W_ + c0;
#pragma unroll
            for (int o = 0; o < 7; ++o) {
                float Z  = acc[o].x;
                float Nm = acc[o].y + nm2[o];
                orow[o] = fmaf(seff * Nm, __builtin_amdgcn_rcpf(Z), sb);
            }
        }

        // ---- transform tile t+1 (xc) into the other buffer ----
        if (t + 1 < NT) {
            v2f (*nbuf)[LCP] = sEF[(t + 1) & 1];
            const int nrow0 = (t + 1) * TRT - PAD;
#pragma unroll
            for (int k = 0; k < 3; ++k) {
                if (ok_[k]) {
                    int gr = nrow0 + r_[k];
                    bool ok = (gr >= 0) && (gr < H_);
                    float4 v = xc[k];
                    float e0 = ok ? __expf(aK * v.x) : 1.0f;
                    float e1 = ok ? __expf(aK * v.y) : 1.0f;
                    float e2 = ok ? __expf(aK * v.z) : 1.0f;
                    float e3 = ok ? __expf(aK * v.w) : 1.0f;
                    float f0 = ok ? (seff * v.x) * e0 : 0.0f;
                    float f1 = ok ? (seff * v.y) * e1 : 0.0f;
                    float f2 = ok ? (seff * v.z) * e2 : 0.0f;
                    float f3 = ok ? (seff * v.w) * e3 : 0.0f;
                    float4* dst = reinterpret_cast<float4*>(&nbuf[r_[k]][2 + 4 * q_[k]]);
                    dst[0] = make_float4(e0, f0, e1, f1);
                    dst[1] = make_float4(e2, f2, e3, f3);
                }
            }
            if (tid < 2 * LRT) {
                int r  = tid >> 1;
                int fi = (tid & 1) ? 114 : 0;
                *reinterpret_cast<float4*>(&nbuf[r][fi]) = make_float4(1.0f, 0.0f, 1.0f, 0.0f);
            }
        }

        // ---- issue tile t+2 loads (land during next iter's compute) ----
        if (t + 2 < NT) {
            const int lrow0 = (t + 2) * TRT - PAD;
#pragma unroll
            for (int k = 0; k < 3; ++k) {
                int grc = min(max(lrow0 + r_[k], 0), H_ - 1);
                xc[k] = *reinterpret_cast<const float4*>(xp + grc * W_ + 4 * q_[k]);
            }
        }

        block_sync_lds();   // single lgkm-drain barrier per iteration
    }
}

extern "C" void kernel_launch(void* const* d_in, const int* in_sizes, int n_in,
                              void* d_out, int out_size, void* d_ws, size_t ws_size,
                              hipStream_t stream) {
    // setup_inputs order: x, weight, bias, sign, padding, stride, func_type, alpha
    const float* x      = (const float*)d_in[0];
    const float* weight = (const float*)d_in[1];
    const float* bias   = (const float*)d_in[2];
    const float* sign   = (const float*)d_in[3];
    const int*   alpha  = (const int*)d_in[7];
    float* out = (float*)d_out;

    dim3 grid(B_ * C_);   // one block per plane
    morpho_pipe<<<grid, TPB, 0, stream>>>(x, weight, bias, sign, alpha, out);
}